// Round 7
// baseline (50.958 us; speedup 1.0000x reference)
//
#include <hip/hip_runtime.h>

typedef __attribute__((ext_vector_type(8))) short bf16x8;
typedef __attribute__((ext_vector_type(4))) float f32x4;
typedef __attribute__((ext_vector_type(8))) _Float16 h16x8;
typedef unsigned short u16;
typedef unsigned int u32;

__device__ __forceinline__ u16 f2bf(float f) {
    u32 x = __builtin_bit_cast(u32, f);
    return (u16)((x + 0x7fffu + ((x >> 16) & 1u)) >> 16);
}
__device__ __forceinline__ u16 f2h(float f) {
    _Float16 h = (_Float16)f;
    return __builtin_bit_cast(u16, h);
}

// ---------------------------------------------------------------------------
// Stage 1 MFMA GEMM: y = relu(BN(w1 @ x)); K=256, M=64, 64n per block.
// Reads x fp32 directly (convert+pack in staging); w1 fp32 + BN fold in-kernel.
// 512 threads = 8 waves: wave (wm 0..3)*16m x (wn 0..1)*32n.
// Output ypk k-packed bf16 [b][kg=8][4096][8].
// ---------------------------------------------------------------------------
__global__ __launch_bounds__(512) void gemm1m_k(
    const float* __restrict__ x,
    const float* __restrict__ w1, const float* __restrict__ gamma,
    const float* __restrict__ beta, const float* __restrict__ mean,
    const float* __restrict__ var,
    u16* __restrict__ ypk)
{
    __shared__ u16 Ws[32 * 64 * 8];    // 32 KB, full K=256 x 64m
    __shared__ u16 As[2][8 * 64 * 8];  // 2 x 8 KB
    const int t = threadIdx.x, lane = t & 63, wave = t >> 6;
    const int b = blockIdx.y, n0 = blockIdx.x * 64;
    const int ln = lane & 15, lk = lane >> 4;
    const int wm = wave >> 1, wn = wave & 1;
    const float* xb = x + (size_t)b * 256 * 4096;

    // stage BN-folded w1 -> bf16 k-packed, m XOR-swizzled by kg&7
    for (int s = t; s < 2048; s += 512) {
        int kg = s >> 6, m = s & 63;
        float sc = gamma[m] * rsqrtf(var[m] + 1e-5f);
        const float4 f0 = *reinterpret_cast<const float4*>(&w1[(size_t)m * 256 + kg * 8]);
        const float4 f1 = *reinterpret_cast<const float4*>(&w1[(size_t)m * 256 + kg * 8 + 4]);
        uint4 v;
        v.x = (u32)f2bf(f0.x * sc) | ((u32)f2bf(f0.y * sc) << 16);
        v.y = (u32)f2bf(f0.z * sc) | ((u32)f2bf(f0.w * sc) << 16);
        v.z = (u32)f2bf(f1.x * sc) | ((u32)f2bf(f1.y * sc) << 16);
        v.w = (u32)f2bf(f1.z * sc) | ((u32)f2bf(f1.w * sc) << 16);
        *reinterpret_cast<uint4*>(&Ws[((kg * 64) + (m ^ (kg & 7))) * 8]) = v;
    }

    const int skg = t >> 6, snn = t & 63;   // this thread's staging pack
    float rx[8];
#pragma unroll
    for (int j = 0; j < 8; ++j)
        rx[j] = xb[(size_t)(skg * 8 + j) * 4096 + n0 + snn];
    {
        uint4 v;
        v.x = (u32)f2bf(rx[0]) | ((u32)f2bf(rx[1]) << 16);
        v.y = (u32)f2bf(rx[2]) | ((u32)f2bf(rx[3]) << 16);
        v.z = (u32)f2bf(rx[4]) | ((u32)f2bf(rx[5]) << 16);
        v.w = (u32)f2bf(rx[6]) | ((u32)f2bf(rx[7]) << 16);
        *reinterpret_cast<uint4*>(&As[0][((skg * 64) + (snn ^ skg)) * 8]) = v;
    }
    __syncthreads();

    f32x4 acc[2];
#pragma unroll
    for (int i = 0; i < 2; ++i)
#pragma unroll
        for (int e = 0; e < 4; ++e) acc[i][e] = 0.f;

    for (int ks = 0; ks < 4; ++ks) {
        const int cur = ks & 1;
        if (ks < 3) {
#pragma unroll
            for (int j = 0; j < 8; ++j)
                rx[j] = xb[(size_t)((ks + 1) * 64 + skg * 8 + j) * 4096 + n0 + snn];
        }
#pragma unroll
        for (int k32 = 0; k32 < 2; ++k32) {
            const int kgl = k32 * 4 + lk;
            const int kgw = ks * 8 + kgl;
            bf16x8 a[2];
#pragma unroll
            for (int i = 0; i < 2; ++i) {
                int n = wn * 32 + i * 16 + ln;
                a[i] = *reinterpret_cast<const bf16x8*>(
                    &As[cur][((kgl * 64) + (n ^ kgl)) * 8]);
            }
            const int m = wm * 16 + ln;
            const bf16x8 bfr = *reinterpret_cast<const bf16x8*>(
                &Ws[((kgw * 64) + (m ^ (kgw & 7))) * 8]);
#pragma unroll
            for (int i = 0; i < 2; ++i)
                acc[i] = __builtin_amdgcn_mfma_f32_16x16x32_bf16(a[i], bfr, acc[i], 0, 0, 0);
        }
        if (ks < 3) {
            uint4 v;
            v.x = (u32)f2bf(rx[0]) | ((u32)f2bf(rx[1]) << 16);
            v.y = (u32)f2bf(rx[2]) | ((u32)f2bf(rx[3]) << 16);
            v.z = (u32)f2bf(rx[4]) | ((u32)f2bf(rx[5]) << 16);
            v.w = (u32)f2bf(rx[6]) | ((u32)f2bf(rx[7]) << 16);
            *reinterpret_cast<uint4*>(&As[cur ^ 1][((skg * 64) + (snn ^ skg)) * 8]) = v;
            __syncthreads();
        }
    }

    // epilogue: m = wm*16+ln; bias+relu; k-packed write
    const int m = wm * 16 + ln;
    const float sc = gamma[m] * rsqrtf(var[m] + 1e-5f);
    const float bv = beta[m] - mean[m] * sc;
    u16* yb = ypk + ((size_t)b * 8 + (m >> 3)) * 4096 * 8 + (m & 7);
#pragma unroll
    for (int i = 0; i < 2; ++i) {
        const int n = n0 + wn * 32 + i * 16 + lk * 4;
#pragma unroll
        for (int r = 0; r < 4; ++r)
            yb[(size_t)(n + r) * 8] = f2bf(fmaxf(acc[i][r] + bv, 0.f));
    }
}

// ---------------------------------------------------------------------------
// Fused weight-gen + involution. Block = (16x16 tile, group, batch).
// Phase 1 (MFMA): wt[256px][49kk] = y[256px][64k] @ w2g[64k][49kk] + b2 -> LDS f16.
// Phase 2 (VALU): out[px][16ch] = sum_kk wt[kk][px] * xpatch (f16 planes).
// w2 converted fp32->bf16 in-kernel; x patches staged fp32->f16 directly.
// ---------------------------------------------------------------------------
__global__ __launch_bounds__(256, 2) void fusedinv_k(
    const u16* __restrict__ ypk, const float* __restrict__ w2,
    const float* __restrict__ b2, const float* __restrict__ x,
    u16* __restrict__ invpk)
{
    __shared__ alignas(16) char Lds[66560];
    u16* As = (u16*)Lds;                   // phase1: [8][256][8] bf16, 32 KB
    u16* Ws = (u16*)(Lds + 32768);         // phase1: [8][64][8] bf16, 8 KB
    _Float16* xs = (_Float16*)Lds;         // phase2: [2][484][8] f16, 15.5 KB
    u16* wt16 = (u16*)(Lds + 40960);       // [49][260] f16, 25.5 KB

    const int t = threadIdx.x, lane = t & 63, wave = t >> 6;
    const int tile = blockIdx.x, g = blockIdx.y, b = blockIdx.z;
    const int ty0 = (tile >> 2) * 16, tx0 = (tile & 3) * 16;
    const int ln = lane & 15, lk = lane >> 4;

    // ---- phase 1 staging: y tile (8kg x 256px) + w2 group slice (fp32->bf16)
    const u16* yb = ypk + (size_t)b * 8 * 4096 * 8;
#pragma unroll
    for (int r = 0; r < 8; ++r) {
        int s = r * 256 + t;               // s = kg*256 + n
        int kg = s >> 8, n = s & 255;
        int gpix = (ty0 + (n >> 4)) * 64 + tx0 + (n & 15);
        *reinterpret_cast<uint4*>(&As[(size_t)s * 8]) =
            *reinterpret_cast<const uint4*>(&yb[((size_t)kg * 4096 + gpix) * 8]);
    }
#pragma unroll
    for (int r = 0; r < 2; ++r) {
        int s = r * 256 + t;               // s = kg*64 + m
        int kg = s >> 6, m = s & 63;
        uint4 v = {0u, 0u, 0u, 0u};
        if (m < 49) {
            const float4 f0 = *reinterpret_cast<const float4*>(
                &w2[(size_t)(g * 49 + m) * 64 + kg * 8]);
            const float4 f1 = *reinterpret_cast<const float4*>(
                &w2[(size_t)(g * 49 + m) * 64 + kg * 8 + 4]);
            v.x = (u32)f2bf(f0.x) | ((u32)f2bf(f0.y) << 16);
            v.y = (u32)f2bf(f0.z) | ((u32)f2bf(f0.w) << 16);
            v.z = (u32)f2bf(f1.x) | ((u32)f2bf(f1.y) << 16);
            v.w = (u32)f2bf(f1.z) | ((u32)f2bf(f1.w) << 16);
        }
        *reinterpret_cast<uint4*>(&Ws[(size_t)s * 8]) = v;
    }
    __syncthreads();

    // ---- phase 1 MFMA: wave owns kk-slice [wave*16, wave*16+16)
    f32x4 acc[16];
#pragma unroll
    for (int i = 0; i < 16; ++i)
#pragma unroll
        for (int e = 0; e < 4; ++e) acc[i][e] = 0.f;

#pragma unroll
    for (int k32 = 0; k32 < 2; ++k32) {
        const int kg = k32 * 4 + lk;
        const bf16x8 wf = *reinterpret_cast<const bf16x8*>(
            &Ws[((kg * 64) + wave * 16 + ln) * 8]);
#pragma unroll
        for (int i = 0; i < 16; ++i) {
            const bf16x8 af = *reinterpret_cast<const bf16x8*>(
                &As[((kg * 256) + i * 16 + ln) * 8]);
            acc[i] = __builtin_amdgcn_mfma_f32_16x16x32_bf16(af, wf, acc[i], 0, 0, 0);
        }
    }
    __syncthreads();   // all As/Ws reads done; region A reusable for xs

    // ---- epilogue: wt -> LDS f16
    const int m = wave * 16 + ln;          // kk index
    if (m < 49) {
        const float bv = b2[g * 49 + m];
#pragma unroll
        for (int i = 0; i < 16; ++i) {
            u16 h0 = f2h(acc[i][0] + bv), h1 = f2h(acc[i][1] + bv);
            u16 h2 = f2h(acc[i][2] + bv), h3 = f2h(acc[i][3] + bv);
            uint2 v;
            v.x = (u32)h0 | ((u32)h1 << 16);
            v.y = (u32)h2 | ((u32)h3 << 16);
            *reinterpret_cast<uint2*>(&wt16[m * 260 + i * 16 + lk * 4]) = v;
        }
    }

    // ---- x patch staging: fp32 -> f16, 2 planes of 8 ch
    const float* xb = x + (size_t)(b * 256 + g * 16) * 4096;
    for (int idx = t; idx < 968; idx += 256) {
        int plane = idx / 484, sp = idx - plane * 484;
        int sy = sp / 22, sx = sp - sy * 22;
        int gy = ty0 + sy - 3, gx = tx0 + sx - 3;
        uint4 h = {0u, 0u, 0u, 0u};
        if ((unsigned)gy < 64u && (unsigned)gx < 64u) {
            const float* xp = &xb[(size_t)(plane * 8) * 4096 + gy * 64 + gx];
            float f[8];
#pragma unroll
            for (int j = 0; j < 8; ++j) f[j] = xp[(size_t)j * 4096];
            h.x = (u32)f2h(f[0]) | ((u32)f2h(f[1]) << 16);
            h.y = (u32)f2h(f[2]) | ((u32)f2h(f[3]) << 16);
            h.z = (u32)f2h(f[4]) | ((u32)f2h(f[5]) << 16);
            h.w = (u32)f2h(f[6]) | ((u32)f2h(f[7]) << 16);
        }
        *reinterpret_cast<uint4*>(&xs[((size_t)plane * 484 + sp) * 8]) = h;
    }
    __syncthreads();

    // ---- phase 2: involution
    const int py = t >> 4, px = t & 15;
    float o[16];
#pragma unroll
    for (int i = 0; i < 16; ++i) o[i] = 0.f;

    for (int dy = 0; dy < 7; ++dy) {
        const int rowb = (py + dy) * 22 + px;
#pragma unroll
        for (int dx = 0; dx < 7; ++dx) {
            const int kk = dy * 7 + dx;
            const float wf = (float)__builtin_bit_cast(_Float16, wt16[kk * 260 + t]);
            const int sp = rowb + dx;
            const h16x8 x0 = *reinterpret_cast<const h16x8*>(&xs[(size_t)sp * 8]);
            const h16x8 x1 = *reinterpret_cast<const h16x8*>(&xs[((size_t)484 + sp) * 8]);
#pragma unroll
            for (int c = 0; c < 8; ++c) {
                o[c]     += wf * (float)x0[c];
                o[8 + c] += wf * (float)x1[c];
            }
        }
    }

    const int pix = (ty0 + py) * 64 + tx0 + px;
#pragma unroll
    for (int h = 0; h < 2; ++h) {
        u16 p[8];
#pragma unroll
        for (int j = 0; j < 8; ++j) p[j] = f2bf(o[h * 8 + j]);
        uint4 v;
        v.x = (u32)p[0] | ((u32)p[1] << 16);
        v.y = (u32)p[2] | ((u32)p[3] << 16);
        v.z = (u32)p[4] | ((u32)p[5] << 16);
        v.w = (u32)p[6] | ((u32)p[7] << 16);
        *reinterpret_cast<uint4*>(
            &invpk[(((size_t)b * 32 + g * 2 + h) * 4096 + pix) * 8]) = v;
    }
}

// ---------------------------------------------------------------------------
// Final MFMA GEMM: out[n][m] = sum_k inv[n][k] * wp[m][k]; K=M=256, fp32 out.
// wp converted fp32->bf16 during LDS staging. Block 64m x 128n.
// ---------------------------------------------------------------------------
__global__ __launch_bounds__(256) void mgemm4_k(
    const u16* __restrict__ Apk,    // invpk [b][32][4096][8]
    const float* __restrict__ wp,   // [256][256] fp32
    float* __restrict__ Cout)
{
    __shared__ u16 As[2][8 * 128 * 8];  // 2 x 16 KB
    __shared__ u16 Ws[32 * 64 * 8];     // 32 KB

    const int t = threadIdx.x;
    const int lane = t & 63, wave = t >> 6;
    const int m0 = blockIdx.x * 64;
    const int batch = blockIdx.y >> 5;
    const int n0 = (blockIdx.y & 31) * 128;
    const u16* Ab = Apk + (size_t)batch * 32 * 4096 * 8;

    const int n0w = (wave & 1) * 64;
    const int m0w = (wave >> 1) * 32;
    const int ln = lane & 15, lk = lane >> 4;

    // stage wp slice -> bf16 k-packed, m XOR-swizzled
    for (int s = t; s < 2048; s += 256) {
        int kg = s >> 6, m = s & 63;
        const float4 f0 = *reinterpret_cast<const float4*>(
            &wp[(size_t)(m0 + m) * 256 + kg * 8]);
        const float4 f1 = *reinterpret_cast<const float4*>(
            &wp[(size_t)(m0 + m) * 256 + kg * 8 + 4]);
        uint4 v;
        v.x = (u32)f2bf(f0.x) | ((u32)f2bf(f0.y) << 16);
        v.y = (u32)f2bf(f0.z) | ((u32)f2bf(f0.w) << 16);
        v.z = (u32)f2bf(f1.x) | ((u32)f2bf(f1.y) << 16);
        v.w = (u32)f2bf(f1.z) | ((u32)f2bf(f1.w) << 16);
        *reinterpret_cast<uint4*>(&Ws[((size_t)kg * 64 + (m ^ (kg & 7))) * 8]) = v;
    }

    uint4 rs[4];
#pragma unroll
    for (int r = 0; r < 4; ++r) {
        int s = r * 256 + t, kg = s >> 7, nn = s & 127;
        rs[r] = *reinterpret_cast<const uint4*>(&Ab[((size_t)kg * 4096 + n0 + nn) * 8]);
    }
#pragma unroll
    for (int r = 0; r < 4; ++r) {
        int s = r * 256 + t, kg = s >> 7, nn = s & 127;
        *reinterpret_cast<uint4*>(&As[0][((size_t)kg * 128 + (nn ^ kg)) * 8]) = rs[r];
    }
    __syncthreads();

    f32x4 acc[4][2];
#pragma unroll
    for (int i = 0; i < 4; ++i)
#pragma unroll
        for (int f = 0; f < 2; ++f)
#pragma unroll
            for (int e = 0; e < 4; ++e) acc[i][f][e] = 0.f;

    for (int ks = 0; ks < 4; ++ks) {
        const int cur = ks & 1;
        if (ks < 3) {
#pragma unroll
            for (int r = 0; r < 4; ++r) {
                int s = r * 256 + t, kg = s >> 7, nn = s & 127;
                rs[r] = *reinterpret_cast<const uint4*>(
                    &Ab[(((size_t)(ks + 1) * 8 + kg) * 4096 + n0 + nn) * 8]);
            }
        }
#pragma unroll
        for (int k32 = 0; k32 < 2; ++k32) {
            const int kg = k32 * 4 + lk;
            bf16x8 a[4], bfr[2];
#pragma unroll
            for (int i = 0; i < 4; ++i) {
                int n = n0w + i * 16 + ln;
                a[i] = *reinterpret_cast<const bf16x8*>(
                    &As[cur][((size_t)kg * 128 + (n ^ kg)) * 8]);
            }
            const int kgw = ks * 8 + kg;
#pragma unroll
            for (int f = 0; f < 2; ++f) {
                int m = m0w + f * 16 + ln;
                bfr[f] = *reinterpret_cast<const bf16x8*>(
                    &Ws[((size_t)kgw * 64 + (m ^ (kgw & 7))) * 8]);
            }
#pragma unroll
            for (int i = 0; i < 4; ++i)
#pragma unroll
                for (int f = 0; f < 2; ++f)
                    acc[i][f] = __builtin_amdgcn_mfma_f32_16x16x32_bf16(
                        a[i], bfr[f], acc[i][f], 0, 0, 0);
        }
        if (ks < 3) {
#pragma unroll
            for (int r = 0; r < 4; ++r) {
                int s = r * 256 + t, kg = s >> 7, nn = s & 127;
                *reinterpret_cast<uint4*>(
                    &As[cur ^ 1][((size_t)kg * 128 + (nn ^ kg)) * 8]) = rs[r];
            }
            __syncthreads();
        }
    }

#pragma unroll
    for (int f = 0; f < 2; ++f) {
        const int m = m0 + m0w + f * 16 + ln;
#pragma unroll
        for (int i = 0; i < 4; ++i) {
            const int n = n0 + n0w + i * 16 + lk * 4;
            float4 v = {acc[i][f][0], acc[i][f][1], acc[i][f][2], acc[i][f][3]};
            *reinterpret_cast<float4*>(&Cout[((size_t)batch * 256 + m) * 4096 + n]) = v;
        }
    }
}

// ---------------------------------------------------------------------------
extern "C" void kernel_launch(void* const* d_in, const int* in_sizes, int n_in,
                              void* d_out, int out_size, void* d_ws, size_t ws_size,
                              hipStream_t stream)
{
    const float* x     = (const float*)d_in[0];
    const float* w1    = (const float*)d_in[1];
    const float* gamma = (const float*)d_in[2];
    const float* beta  = (const float*)d_in[3];
    const float* mean  = (const float*)d_in[4];
    const float* var   = (const float*)d_in[5];
    const float* w2    = (const float*)d_in[6];
    const float* b2    = (const float*)d_in[7];
    const float* wp    = (const float*)d_in[8];
    float* out = (float*)d_out;

    u16* u = (u16*)d_ws;
    u16* ypk   = u;                 // 4*8*4096*8  = 1,048,576
    u16* invpk = u + 1048576;       // 4*32*4096*8 = 4,194,304  (~10.5 MB total)

    // y = relu(BN(w1 @ x)) -> k-packed bf16
    gemm1m_k<<<dim3(64, 4), 512, 0, stream>>>(x, w1, gamma, beta, mean, var, ypk);
    // fused: wt = w2g @ y + b2 (MFMA, in-LDS) ; inv = involution(x, wt)
    fusedinv_k<<<dim3(16, 16, 4), 256, 0, stream>>>(ypk, w2, b2, x, invpk);
    // out = wp @ inv  (K=256, M=256) -> fp32
    mgemm4_k<<<dim3(4, 128), 256, 0, stream>>>(invpk, wp, out);
}

// Round 8
// 49.228 us; speedup vs baseline: 1.0351x; 1.0351x over previous
//
#include <hip/hip_runtime.h>

typedef __attribute__((ext_vector_type(8))) short bf16x8;
typedef __attribute__((ext_vector_type(4))) float f32x4;
typedef __attribute__((ext_vector_type(8))) _Float16 h16x8;
typedef unsigned short u16;
typedef unsigned int u32;

__device__ __forceinline__ u16 f2bf(float f) {
    u32 x = __builtin_bit_cast(u32, f);
    return (u16)((x + 0x7fffu + ((x >> 16) & 1u)) >> 16);
}
__device__ __forceinline__ u16 f2h(float f) {
    _Float16 h = (_Float16)f;
    return __builtin_bit_cast(u16, h);
}

// ---------------------------------------------------------------------------
// Stage 1 MFMA GEMM (swapped roles): y[m][n] = relu(sum_k w1bn[m][k]*x[k][n]).
// K=256, M=64, 64n per block, 512 threads = 8 waves (wm 0..3 m-tile, wn 0..1
// n-pair). D rows = m -> each lane holds 4 consecutive m of one kg-group =>
// ypk written as coalesced uint2 (no scalar stores).
// ypk layout: [b][kg=8][4096n][8j] bf16.
// ---------------------------------------------------------------------------
__global__ __launch_bounds__(512) void gemm1m_k(
    const float* __restrict__ x,
    const float* __restrict__ w1, const float* __restrict__ gamma,
    const float* __restrict__ beta, const float* __restrict__ mean,
    const float* __restrict__ var,
    u16* __restrict__ ypk)
{
    __shared__ u16 Ws[32 * 64 * 8];    // [kg32][m64 swz][8], 32 KB
    __shared__ u16 As[2][8 * 64 * 8];  // [kg8][n64 swz][8], 2 x 8 KB

    const int t = threadIdx.x, lane = t & 63, wave = t >> 6;
    const int b = blockIdx.y, n0 = blockIdx.x * 64;
    const int ln = lane & 15, lk = lane >> 4;
    const int wm = wave >> 1, wn = wave & 1;
    const float* xb = x + (size_t)b * 256 * 4096;

    // stage BN-folded w1 -> bf16 k-packed, m XOR-swizzled by kg&7
    for (int s = t; s < 2048; s += 512) {
        int kg = s >> 6, m = s & 63;
        float sc = gamma[m] * rsqrtf(var[m] + 1e-5f);
        const float4 f0 = *reinterpret_cast<const float4*>(&w1[(size_t)m * 256 + kg * 8]);
        const float4 f1 = *reinterpret_cast<const float4*>(&w1[(size_t)m * 256 + kg * 8 + 4]);
        uint4 v;
        v.x = (u32)f2bf(f0.x * sc) | ((u32)f2bf(f0.y * sc) << 16);
        v.y = (u32)f2bf(f0.z * sc) | ((u32)f2bf(f0.w * sc) << 16);
        v.z = (u32)f2bf(f1.x * sc) | ((u32)f2bf(f1.y * sc) << 16);
        v.w = (u32)f2bf(f1.z * sc) | ((u32)f2bf(f1.w * sc) << 16);
        *reinterpret_cast<uint4*>(&Ws[((kg * 64) + (m ^ (kg & 7))) * 8]) = v;
    }

    const int skg = t >> 6, snn = t & 63;   // staging: wave=kg-slice, lane=n
    float rx[8];
#pragma unroll
    for (int j = 0; j < 8; ++j)
        rx[j] = xb[(size_t)(skg * 8 + j) * 4096 + n0 + snn];
    {
        uint4 v;
        v.x = (u32)f2bf(rx[0]) | ((u32)f2bf(rx[1]) << 16);
        v.y = (u32)f2bf(rx[2]) | ((u32)f2bf(rx[3]) << 16);
        v.z = (u32)f2bf(rx[4]) | ((u32)f2bf(rx[5]) << 16);
        v.w = (u32)f2bf(rx[6]) | ((u32)f2bf(rx[7]) << 16);
        *reinterpret_cast<uint4*>(&As[0][((skg * 64) + (snn ^ skg)) * 8]) = v;
    }
    __syncthreads();

    f32x4 acc[2];
#pragma unroll
    for (int i = 0; i < 2; ++i)
#pragma unroll
        for (int e = 0; e < 4; ++e) acc[i][e] = 0.f;

    for (int ks = 0; ks < 4; ++ks) {
        const int cur = ks & 1;
        if (ks < 3) {
#pragma unroll
            for (int j = 0; j < 8; ++j)
                rx[j] = xb[(size_t)((ks + 1) * 64 + skg * 8 + j) * 4096 + n0 + snn];
        }
#pragma unroll
        for (int k32 = 0; k32 < 2; ++k32) {
            const int kgl = k32 * 4 + lk;
            const int kgw = ks * 8 + kgl;
            // A-frag: w1 rows m
            const bf16x8 aw = *reinterpret_cast<const bf16x8*>(
                &Ws[((kgw * 64) + ((wm * 16 + ln) ^ (kgw & 7))) * 8]);
            // B-frags: x cols n
#pragma unroll
            for (int i = 0; i < 2; ++i) {
                const int n = wn * 32 + i * 16 + ln;
                const bf16x8 bx = *reinterpret_cast<const bf16x8*>(
                    &As[cur][((kgl * 64) + (n ^ kgl)) * 8]);
                acc[i] = __builtin_amdgcn_mfma_f32_16x16x32_bf16(aw, bx, acc[i], 0, 0, 0);
            }
        }
        if (ks < 3) {
            uint4 v;
            v.x = (u32)f2bf(rx[0]) | ((u32)f2bf(rx[1]) << 16);
            v.y = (u32)f2bf(rx[2]) | ((u32)f2bf(rx[3]) << 16);
            v.z = (u32)f2bf(rx[4]) | ((u32)f2bf(rx[5]) << 16);
            v.w = (u32)f2bf(rx[6]) | ((u32)f2bf(rx[7]) << 16);
            *reinterpret_cast<uint4*>(&As[cur ^ 1][((skg * 64) + (snn ^ skg)) * 8]) = v;
            __syncthreads();
        }
    }

    // epilogue: lane holds rows m = wm*16 + lk*4 + r (r=0..3), col n = ln.
    const int mb = wm * 16 + lk * 4;
    const float4 g4 = *reinterpret_cast<const float4*>(&gamma[mb]);
    const float4 v4 = *reinterpret_cast<const float4*>(&var[mb]);
    const float4 be4 = *reinterpret_cast<const float4*>(&beta[mb]);
    const float4 mn4 = *reinterpret_cast<const float4*>(&mean[mb]);
    float bv[4];
    bv[0] = be4.x - mn4.x * (g4.x * rsqrtf(v4.x + 1e-5f));
    bv[1] = be4.y - mn4.y * (g4.y * rsqrtf(v4.y + 1e-5f));
    bv[2] = be4.z - mn4.z * (g4.z * rsqrtf(v4.z + 1e-5f));
    bv[3] = be4.w - mn4.w * (g4.w * rsqrtf(v4.w + 1e-5f));
    const int kg = mb >> 3, joff = mb & 7;   // joff in {0,4}
#pragma unroll
    for (int i = 0; i < 2; ++i) {
        const int n = n0 + wn * 32 + i * 16 + ln;
        u16 p[4];
#pragma unroll
        for (int r = 0; r < 4; ++r)
            p[r] = f2bf(fmaxf(acc[i][r] + bv[r], 0.f));
        uint2 v;
        v.x = (u32)p[0] | ((u32)p[1] << 16);
        v.y = (u32)p[2] | ((u32)p[3] << 16);
        *reinterpret_cast<uint2*>(
            &ypk[(((size_t)b * 8 + kg) * 4096 + n) * 8 + joff]) = v;
    }
}

// ---------------------------------------------------------------------------
// Fused weight-gen + involution. Block = (16x16 tile, group, batch), 512 th.
// Phase 1 (MFMA, 8 waves = 4 kk-quarters x 2 px-halves):
//   wt[256px][49kk] = y[256px][64k] @ w2g[64k][49kk] + b2 -> LDS f16.
// Phase 2 (VALU, thread = (px, ch-half)): out[px][8ch] = sum_kk wt*xs.
// ---------------------------------------------------------------------------
__global__ __launch_bounds__(512, 4) void fusedinv_k(
    const u16* __restrict__ ypk, const float* __restrict__ w2,
    const float* __restrict__ b2, const float* __restrict__ x,
    u16* __restrict__ invpk)
{
    __shared__ alignas(16) char Lds[66560];
    u16* As = (u16*)Lds;                   // phase1: [8kg][256px swz][8], 32 KB
    u16* Ws = (u16*)(Lds + 32768);         // phase1: [8kg][64kk swz][8], 8 KB
    _Float16* xs = (_Float16*)Lds;         // phase2: [2][484][8] f16, 15.5 KB
    u16* wt16 = (u16*)(Lds + 40960);       // [49][260] f16, 25.5 KB

    const int t = threadIdx.x, lane = t & 63, wave = t >> 6;
    const int tile = blockIdx.x, g = blockIdx.y, b = blockIdx.z;
    const int ty0 = (tile >> 2) * 16, tx0 = (tile & 3) * 16;
    const int ln = lane & 15, lk = lane >> 4;
    const int q = wave >> 1, h = wave & 1;

    // ---- phase 1 staging: y tile (XOR-swizzled) + w2 group slice
    const u16* yb = ypk + (size_t)b * 8 * 4096 * 8;
#pragma unroll
    for (int r = 0; r < 4; ++r) {
        int s = r * 512 + t;               // s = kg*256 + n
        int kg = s >> 8, n = s & 255;
        int gpix = (ty0 + (n >> 4)) * 64 + tx0 + (n & 15);
        *reinterpret_cast<uint4*>(&As[((kg * 256) + (n ^ kg)) * 8]) =
            *reinterpret_cast<const uint4*>(&yb[((size_t)kg * 4096 + gpix) * 8]);
    }
    {
        int kg = t >> 6, m = t & 63;
        uint4 v = {0u, 0u, 0u, 0u};
        if (m < 49) {
            const float4 f0 = *reinterpret_cast<const float4*>(
                &w2[(size_t)(g * 49 + m) * 64 + kg * 8]);
            const float4 f1 = *reinterpret_cast<const float4*>(
                &w2[(size_t)(g * 49 + m) * 64 + kg * 8 + 4]);
            v.x = (u32)f2bf(f0.x) | ((u32)f2bf(f0.y) << 16);
            v.y = (u32)f2bf(f0.z) | ((u32)f2bf(f0.w) << 16);
            v.z = (u32)f2bf(f1.x) | ((u32)f2bf(f1.y) << 16);
            v.w = (u32)f2bf(f1.z) | ((u32)f2bf(f1.w) << 16);
        }
        *reinterpret_cast<uint4*>(&Ws[((kg * 64) + (m ^ kg)) * 8]) = v;
    }
    __syncthreads();

    // ---- phase 1 MFMA: wave (q,h): kk-tile q, px-tiles h*8+i (i=0..7)
    f32x4 acc[8];
#pragma unroll
    for (int i = 0; i < 8; ++i)
#pragma unroll
        for (int e = 0; e < 4; ++e) acc[i][e] = 0.f;

#pragma unroll
    for (int k32 = 0; k32 < 2; ++k32) {
        const int kg = k32 * 4 + lk;
        const bf16x8 wf = *reinterpret_cast<const bf16x8*>(
            &Ws[((kg * 64) + ((q * 16 + ln) ^ kg)) * 8]);
#pragma unroll
        for (int i = 0; i < 8; ++i) {
            const int n = (h * 8 + i) * 16 + ln;
            const bf16x8 af = *reinterpret_cast<const bf16x8*>(
                &As[((kg * 256) + (n ^ kg)) * 8]);
            acc[i] = __builtin_amdgcn_mfma_f32_16x16x32_bf16(af, wf, acc[i], 0, 0, 0);
        }
    }
    __syncthreads();   // As/Ws reads done; region reusable for xs

    // ---- epilogue: wt -> LDS f16 (col kk = q*16+ln, rows px)
    const int kk = q * 16 + ln;
    if (kk < 49) {
        const float bv = b2[g * 49 + kk];
#pragma unroll
        for (int i = 0; i < 8; ++i) {
            u16 h0 = f2h(acc[i][0] + bv), h1 = f2h(acc[i][1] + bv);
            u16 h2 = f2h(acc[i][2] + bv), h3 = f2h(acc[i][3] + bv);
            uint2 v;
            v.x = (u32)h0 | ((u32)h1 << 16);
            v.y = (u32)h2 | ((u32)h3 << 16);
            *reinterpret_cast<uint2*>(&wt16[kk * 260 + (h * 8 + i) * 16 + lk * 4]) = v;
        }
    }

    // ---- x patch staging: fp32 -> f16, 2 planes of 8 ch
    const float* xb = x + (size_t)(b * 256 + g * 16) * 4096;
    for (int idx = t; idx < 968; idx += 512) {
        int plane = idx / 484, sp = idx - plane * 484;
        int sy = sp / 22, sx = sp - sy * 22;
        int gy = ty0 + sy - 3, gx = tx0 + sx - 3;
        uint4 hh = {0u, 0u, 0u, 0u};
        if ((unsigned)gy < 64u && (unsigned)gx < 64u) {
            const float* xp = &xb[(size_t)(plane * 8) * 4096 + gy * 64 + gx];
            float f[8];
#pragma unroll
            for (int j = 0; j < 8; ++j) f[j] = xp[(size_t)j * 4096];
            hh.x = (u32)f2h(f[0]) | ((u32)f2h(f[1]) << 16);
            hh.y = (u32)f2h(f[2]) | ((u32)f2h(f[3]) << 16);
            hh.z = (u32)f2h(f[4]) | ((u32)f2h(f[5]) << 16);
            hh.w = (u32)f2h(f[6]) | ((u32)f2h(f[7]) << 16);
        }
        *reinterpret_cast<uint4*>(&xs[((size_t)plane * 484 + sp) * 8]) = hh;
    }
    __syncthreads();

    // ---- phase 2: involution; thread = (px, half), 8 channels
    const int px = t & 255, half = t >> 8;
    const int py = px >> 4, pxx = px & 15;
    float o[8];
#pragma unroll
    for (int i = 0; i < 8; ++i) o[i] = 0.f;

    for (int dy = 0; dy < 7; ++dy) {
        const int rowb = (py + dy) * 22 + pxx;
#pragma unroll
        for (int dx = 0; dx < 7; ++dx) {
            const int kkx = dy * 7 + dx;
            const float wf = (float)__builtin_bit_cast(_Float16, wt16[kkx * 260 + px]);
            const h16x8 xv = *reinterpret_cast<const h16x8*>(
                &xs[((size_t)half * 484 + rowb + dx) * 8]);
#pragma unroll
            for (int c = 0; c < 8; ++c)
                o[c] += wf * (float)xv[c];
        }
    }

    const int pix = (ty0 + py) * 64 + tx0 + pxx;
    u16 p[8];
#pragma unroll
    for (int j = 0; j < 8; ++j) p[j] = f2bf(o[j]);
    uint4 v;
    v.x = (u32)p[0] | ((u32)p[1] << 16);
    v.y = (u32)p[2] | ((u32)p[3] << 16);
    v.z = (u32)p[4] | ((u32)p[5] << 16);
    v.w = (u32)p[6] | ((u32)p[7] << 16);
    *reinterpret_cast<uint4*>(
        &invpk[(((size_t)b * 32 + g * 2 + half) * 4096 + pix) * 8]) = v;
}

// ---------------------------------------------------------------------------
// Final MFMA GEMM: out[n][m] = sum_k inv[n][k] * wp[m][k]; K=M=256, fp32 out.
// 512 threads = 8 waves (wn 0..3 n-quarter, wm 0..1 m-half). Block 64m x 128n.
// ---------------------------------------------------------------------------
__global__ __launch_bounds__(512, 4) void mgemm4_k(
    const u16* __restrict__ Apk,    // invpk [b][32][4096][8]
    const float* __restrict__ wp,   // [256][256] fp32
    float* __restrict__ Cout)
{
    __shared__ u16 As[2][8 * 128 * 8];  // 2 x 16 KB
    __shared__ u16 Ws[32 * 64 * 8];     // 32 KB

    const int t = threadIdx.x;
    const int lane = t & 63, wave = t >> 6;
    const int m0 = blockIdx.x * 64;
    const int batch = blockIdx.y >> 5;
    const int n0 = (blockIdx.y & 31) * 128;
    const u16* Ab = Apk + (size_t)batch * 32 * 4096 * 8;

    const int wn = wave & 3, wm = wave >> 2;
    const int ln = lane & 15, lk = lane >> 4;

    // stage wp slice -> bf16 k-packed, m XOR-swizzled
    for (int s = t; s < 2048; s += 512) {
        int kg = s >> 6, m = s & 63;
        const float4 f0 = *reinterpret_cast<const float4*>(
            &wp[(size_t)(m0 + m) * 256 + kg * 8]);
        const float4 f1 = *reinterpret_cast<const float4*>(
            &wp[(size_t)(m0 + m) * 256 + kg * 8 + 4]);
        uint4 v;
        v.x = (u32)f2bf(f0.x) | ((u32)f2bf(f0.y) << 16);
        v.y = (u32)f2bf(f0.z) | ((u32)f2bf(f0.w) << 16);
        v.z = (u32)f2bf(f1.x) | ((u32)f2bf(f1.y) << 16);
        v.w = (u32)f2bf(f1.z) | ((u32)f2bf(f1.w) << 16);
        *reinterpret_cast<uint4*>(&Ws[((size_t)kg * 64 + (m ^ (kg & 7))) * 8]) = v;
    }

    uint4 rs[2];
#pragma unroll
    for (int r = 0; r < 2; ++r) {
        int s = r * 512 + t, kg = s >> 7, nn = s & 127;
        rs[r] = *reinterpret_cast<const uint4*>(&Ab[((size_t)kg * 4096 + n0 + nn) * 8]);
    }
#pragma unroll
    for (int r = 0; r < 2; ++r) {
        int s = r * 512 + t, kg = s >> 7, nn = s & 127;
        *reinterpret_cast<uint4*>(&As[0][((size_t)kg * 128 + (nn ^ kg)) * 8]) = rs[r];
    }
    __syncthreads();

    f32x4 acc[2][2];
#pragma unroll
    for (int i = 0; i < 2; ++i)
#pragma unroll
        for (int f = 0; f < 2; ++f)
#pragma unroll
            for (int e = 0; e < 4; ++e) acc[i][f][e] = 0.f;

    for (int ks = 0; ks < 4; ++ks) {
        const int cur = ks & 1;
        if (ks < 3) {
#pragma unroll
            for (int r = 0; r < 2; ++r) {
                int s = r * 512 + t, kg = s >> 7, nn = s & 127;
                rs[r] = *reinterpret_cast<const uint4*>(
                    &Ab[(((size_t)(ks + 1) * 8 + kg) * 4096 + n0 + nn) * 8]);
            }
        }
#pragma unroll
        for (int k32 = 0; k32 < 2; ++k32) {
            const int kg = k32 * 4 + lk;
            const int kgw = ks * 8 + kg;
            bf16x8 a[2], bfr[2];
#pragma unroll
            for (int i = 0; i < 2; ++i) {
                int n = wn * 32 + i * 16 + ln;
                a[i] = *reinterpret_cast<const bf16x8*>(
                    &As[cur][((size_t)kg * 128 + (n ^ kg)) * 8]);
            }
#pragma unroll
            for (int f = 0; f < 2; ++f) {
                int m = wm * 32 + f * 16 + ln;
                bfr[f] = *reinterpret_cast<const bf16x8*>(
                    &Ws[((size_t)kgw * 64 + (m ^ (kgw & 7))) * 8]);
            }
#pragma unroll
            for (int i = 0; i < 2; ++i)
#pragma unroll
                for (int f = 0; f < 2; ++f)
                    acc[i][f] = __builtin_amdgcn_mfma_f32_16x16x32_bf16(
                        a[i], bfr[f], acc[i][f], 0, 0, 0);
        }
        if (ks < 3) {
#pragma unroll
            for (int r = 0; r < 2; ++r) {
                int s = r * 512 + t, kg = s >> 7, nn = s & 127;
                *reinterpret_cast<uint4*>(
                    &As[cur ^ 1][((size_t)kg * 128 + (nn ^ kg)) * 8]) = rs[r];
            }
            __syncthreads();
        }
    }

#pragma unroll
    for (int f = 0; f < 2; ++f) {
        const int m = m0 + wm * 32 + f * 16 + ln;
#pragma unroll
        for (int i = 0; i < 2; ++i) {
            const int n = n0 + wn * 32 + i * 16 + lk * 4;
            float4 v = {acc[i][f][0], acc[i][f][1], acc[i][f][2], acc[i][f][3]};
            *reinterpret_cast<float4*>(&Cout[((size_t)batch * 256 + m) * 4096 + n]) = v;
        }
    }
}

// ---------------------------------------------------------------------------
extern "C" void kernel_launch(void* const* d_in, const int* in_sizes, int n_in,
                              void* d_out, int out_size, void* d_ws, size_t ws_size,
                              hipStream_t stream)
{
    const float* x     = (const float*)d_in[0];
    const float* w1    = (const float*)d_in[1];
    const float* gamma = (const float*)d_in[2];
    const float* beta  = (const float*)d_in[3];
    const float* mean  = (const float*)d_in[4];
    const float* var   = (const float*)d_in[5];
    const float* w2    = (const float*)d_in[6];
    const float* b2    = (const float*)d_in[7];
    const float* wp    = (const float*)d_in[8];
    float* out = (float*)d_out;

    u16* u = (u16*)d_ws;
    u16* ypk   = u;                 // 4*8*4096*8  = 1,048,576
    u16* invpk = u + 1048576;       // 4*32*4096*8 = 4,194,304  (~10.5 MB total)

    // y = relu(BN(w1 @ x)) -> k-packed bf16
    gemm1m_k<<<dim3(64, 4), 512, 0, stream>>>(x, w1, gamma, beta, mean, var, ypk);
    // fused: wt = w2g @ y + b2 (MFMA, in-LDS) ; inv = involution(x, wt)
    fusedinv_k<<<dim3(16, 16, 4), 512, 0, stream>>>(ypk, w2, b2, x, invpk);
    // out = wp @ inv  (K=256, M=256) -> fp32
    mgemm4_k<<<dim3(4, 128), 512, 0, stream>>>(invpk, wp, out);
}